// Round 2
// baseline (160.801 us; speedup 1.0000x reference)
//
#include <hip/hip_runtime.h>
#include <stdint.h>

#define HID 768
#define HD  64
#define NB  8
#define SEQ 2048

typedef __bf16 bf16_t;
typedef __bf16 bf16x8 __attribute__((ext_vector_type(8)));
typedef __bf16 bf16x4 __attribute__((ext_vector_type(4)));
typedef float  f32x4  __attribute__((ext_vector_type(4)));
typedef unsigned int u32x4 __attribute__((ext_vector_type(4)));

// workspace layout (bytes)
#define WT_OFF 0                         // bf16 WT[3][64][768]
#define B_OFF  (3*HD*HID*2)              // f32  bias[3][64]   (=294912)
#define Q_OFF  (512*1024)                // bf16 q[16384][64]
#define K_OFF  (Q_OFF + NB*SEQ*HD*2)
#define V_OFF  (K_OFF + NB*SEQ*HD*2)
#define WS_NEED ((size_t)(V_OFF + NB*SEQ*HD*2))

#define ALPHA 0.18033688011112043f       // log2(e) / sqrt(64)

// ---------------- kernel 1: convert + transpose weights, fold scale ----------
__global__ __launch_bounds__(256) void cvt_kernel(
    const float* __restrict__ Wq, const float* __restrict__ bq,
    const float* __restrict__ Wk, const float* __restrict__ bk,
    const float* __restrict__ Wv, const float* __restrict__ bv,
    uint8_t* __restrict__ ws) {
  bf16_t* wt = (bf16_t*)(ws + WT_OFF);
  float*  bs = (float*)(ws + B_OFF);
  int idx = blockIdx.x * 256 + threadIdx.x;   // enumerates (t, h, n) -> coalesced read
  if (idx < 3 * HID * HD) {
    int n = idx & 63;
    int h = (idx >> 6) % HID;
    int t = idx / (HID * HD);
    const float* W = (t == 0) ? Wq : (t == 1) ? Wk : Wv;
    float v = W[h * HD + n];
    if (t == 0) v *= ALPHA;                    // prescale q path
    wt[(size_t)(t * HD + n) * HID + h] = (bf16_t)v;   // WT[t][n][h]
  }
  if (idx < 3 * HD) {
    int t = idx / HD, n = idx % HD;
    const float* bsrc = (t == 0) ? bq : (t == 1) ? bk : bv;
    bs[idx] = bsrc[n] * ((t == 0) ? ALPHA : 1.0f);
  }
}

// ---------------- kernel 2: projections  out[t] = X * W + b  (bf16 MFMA) -----
// swapped operands: D[i=out_col][j=x_row] = sum_k WT[n][k] * X[m][k]
__global__ __launch_bounds__(256) void proj_kernel(
    const float* __restrict__ qin, const float* __restrict__ kin,
    const float* __restrict__ vin, uint8_t* __restrict__ ws) {
  const int t = blockIdx.y;
  const float* X = (t == 0) ? qin : (t == 1) ? kin : vin;
  const bf16_t* wt = (const bf16_t*)(ws + WT_OFF) + (size_t)t * HD * HID;
  const float* bias = (const float*)(ws + B_OFF) + t * HD;
  bf16_t* out = (bf16_t*)(ws + Q_OFF) + (size_t)t * NB * SEQ * HD;

  const int tid  = threadIdx.x;
  const int wid  = tid >> 6;
  const int lane = tid & 63;
  const int lm   = lane & 15;     // A-row (out col) and B-col (x row)
  const int kg   = lane >> 4;     // k-group: k = kg*8 + j
  const int r0   = blockIdx.x * 64 + wid * 16;

  f32x4 acc[4] = {{0,0,0,0},{0,0,0,0},{0,0,0,0},{0,0,0,0}};
  const float*  xp = X  + (size_t)(r0 + lm) * HID + kg * 8;
  const bf16_t* wp = wt + (size_t)lm * HID + kg * 8;

  #pragma unroll 2
  for (int kk = 0; kk < 24; ++kk) {
    f32x4 x0 = *(const f32x4*)(xp + kk * 32);
    f32x4 x1 = *(const f32x4*)(xp + kk * 32 + 4);
    bf16x8 xb;
    xb[0] = (bf16_t)x0[0]; xb[1] = (bf16_t)x0[1];
    xb[2] = (bf16_t)x0[2]; xb[3] = (bf16_t)x0[3];
    xb[4] = (bf16_t)x1[0]; xb[5] = (bf16_t)x1[1];
    xb[6] = (bf16_t)x1[2]; xb[7] = (bf16_t)x1[3];
    #pragma unroll
    for (int c = 0; c < 4; ++c) {
      bf16x8 wf = *(const bf16x8*)(wp + (size_t)c * 16 * HID + kk * 32);
      acc[c] = __builtin_amdgcn_mfma_f32_16x16x32_bf16(wf, xb, acc[c], 0, 0, 0);
    }
  }
  // D: col(lane&15)=x_row, row((lane>>4)*4+reg)=out_col -> 4 consecutive out cols per lane
  #pragma unroll
  for (int c = 0; c < 4; ++c) {
    f32x4 b4 = *(const f32x4*)(bias + c * 16 + kg * 4);
    bf16x4 pk;
    pk[0] = (bf16_t)(acc[c][0] + b4[0]);
    pk[1] = (bf16_t)(acc[c][1] + b4[1]);
    pk[2] = (bf16_t)(acc[c][2] + b4[2]);
    pk[3] = (bf16_t)(acc[c][3] + b4[3]);
    *(bf16x4*)(out + (size_t)(r0 + lm) * HD + c * 16 + kg * 4) = pk;
  }
}

// ---------------- kernel 3: flash attention ---------------------------------
// block = 128 threads (2 waves), each wave owns 16 q rows; KV tile = 64.
__global__ __launch_bounds__(128) void attn_kernel(
    const uint8_t* __restrict__ ws, const int* __restrict__ mask,
    float* __restrict__ out) {
  __shared__ __align__(16) uint8_t smem[2 * 2048 + 64 * 128];  // P[2 waves] + Vt
  const int b    = blockIdx.y;
  const int tid  = threadIdx.x;
  const int wid  = tid >> 6;
  const int lane = tid & 63;
  const int lm   = lane & 15;
  const int kg   = lane >> 4;

  const bf16_t* qb = (const bf16_t*)(ws + Q_OFF);
  const bf16_t* kbase = (const bf16_t*)(ws + K_OFF) + (size_t)b * SEQ * HD;
  const bf16_t* vbase = (const bf16_t*)(ws + V_OFF) + (size_t)b * SEQ * HD;
  const int* mp = mask + b * SEQ;

  const size_t qrow0 = (size_t)b * SEQ + blockIdx.x * 32 + wid * 16;
  bf16x8 qa0 = *(const bf16x8*)(qb + (qrow0 + lm) * HD + kg * 8);
  bf16x8 qa1 = *(const bf16x8*)(qb + (qrow0 + lm) * HD + 32 + kg * 8);

  f32x4 o[4] = {{0,0,0,0},{0,0,0,0},{0,0,0,0},{0,0,0,0}};
  float mrow[4] = {-1e30f, -1e30f, -1e30f, -1e30f};
  float lrow[4] = {0.f, 0.f, 0.f, 0.f};

  uint8_t* Pl = smem + wid * 2048;   // wave-private P tile, XOR-swizzled
  uint8_t* Vt = smem + 4096;         // transposed V tile [d][kv], XOR-swizzled

  for (int kv0 = 0; kv0 < SEQ; kv0 += 64) {
    __syncthreads();                 // prev tile's Vt reads done
    // issue V stage loads early.
    // V tile = 64 rows x 128 B = 512 16B-chunks; 128 threads x 4 chunks each.
    // chunk c: row = c>>3, elem offset = (c&7)*8.
    u32x4 st[4];
    #pragma unroll
    for (int m = 0; m < 4; ++m) {
      int c = tid + 128 * m;
      st[m] = *(const u32x4*)(vbase + (size_t)(kv0 + (c >> 3)) * HD + (c & 7) * 8);
    }

    // QK^T: A=Q rows, B=K rows (contiguous 16B per lane from row-major K)
    f32x4 sc[4];
    #pragma unroll
    for (int nf = 0; nf < 4; ++nf) {
      const bf16_t* kp = kbase + (size_t)(kv0 + nf * 16 + lm) * HD + kg * 8;
      bf16x8 k0 = *(const bf16x8*)(kp);
      bf16x8 k1 = *(const bf16x8*)(kp + 32);
      f32x4 z = {0.f, 0.f, 0.f, 0.f};
      z = __builtin_amdgcn_mfma_f32_16x16x32_bf16(qa0, k0, z, 0, 0, 0);
      z = __builtin_amdgcn_mfma_f32_16x16x32_bf16(qa1, k1, z, 0, 0, 0);
      sc[nf] = z;
    }
    // mask (col = lane&15 for all 4 regs)
    #pragma unroll
    for (int nf = 0; nf < 4; ++nf)
      if (mp[kv0 + nf * 16 + lm] == 0) {
        sc[nf][0] = -1e30f; sc[nf][1] = -1e30f; sc[nf][2] = -1e30f; sc[nf][3] = -1e30f;
      }
    // online softmax (base-2 domain; scale pre-folded into q)
    float corr[4];
    #pragma unroll
    for (int i = 0; i < 4; ++i) {
      float tmx = fmaxf(fmaxf(sc[0][i], sc[1][i]), fmaxf(sc[2][i], sc[3][i]));
      tmx = fmaxf(tmx, __shfl_xor(tmx, 1));
      tmx = fmaxf(tmx, __shfl_xor(tmx, 2));
      tmx = fmaxf(tmx, __shfl_xor(tmx, 4));
      tmx = fmaxf(tmx, __shfl_xor(tmx, 8));
      float mn = fmaxf(mrow[i], tmx);
      corr[i] = __builtin_amdgcn_exp2f(mrow[i] - mn);
      mrow[i] = mn;
    }
    float ps[4] = {0.f, 0.f, 0.f, 0.f};
    #pragma unroll
    for (int nf = 0; nf < 4; ++nf) {
      #pragma unroll
      for (int i = 0; i < 4; ++i) {
        float p = __builtin_amdgcn_exp2f(sc[nf][i] - mrow[i]);
        sc[nf][i] = p;
        ps[i] += p;
      }
    }
    #pragma unroll
    for (int i = 0; i < 4; ++i) {
      float s = ps[i];
      s += __shfl_xor(s, 1); s += __shfl_xor(s, 2);
      s += __shfl_xor(s, 4); s += __shfl_xor(s, 8);
      lrow[i] = lrow[i] * corr[i] + s;
    }
    #pragma unroll
    for (int nf = 0; nf < 4; ++nf) {
      o[nf][0] *= corr[0]; o[nf][1] *= corr[1];
      o[nf][2] *= corr[2]; o[nf][3] *= corr[3];
    }
    // P -> wave-private LDS (bf16, row*128 + col*2, ^((row&7)<<4))
    #pragma unroll
    for (int nf = 0; nf < 4; ++nf) {
      #pragma unroll
      for (int i = 0; i < 4; ++i) {
        int row = kg * 4 + i;
        unsigned by = (unsigned)(row * 128 + (nf * 16 + lm) * 2) ^ (unsigned)((row & 7) << 4);
        *(bf16_t*)(Pl + by) = (bf16_t)sc[nf][i];
      }
    }
    // P A-frags back (same-wave, compiler inserts lgkmcnt)
    bf16x8 pa0, pa1;
    { unsigned by = (unsigned)(lm * 128 + kg * 16)      ^ (unsigned)((lm & 7) << 4); pa0 = *(const bf16x8*)(Pl + by); }
    { unsigned by = (unsigned)(lm * 128 + 64 + kg * 16) ^ (unsigned)((lm & 7) << 4); pa1 = *(const bf16x8*)(Pl + by); }
    // write V transposed into LDS: Vt[d][kv], byte = d*128+kv*2 ^ (((d&7)^((d>>3)&7))<<4)
    #pragma unroll
    for (int m = 0; m < 4; ++m) {
      union { u32x4 v4; unsigned short s[8]; } u;
      u.v4 = st[m];
      const int c   = tid + 128 * m;
      const int row = c >> 3;          // kv within tile
      const int d8  = (c & 7) * 8;     // head-dim start
      #pragma unroll
      for (int j = 0; j < 8; ++j) {
        int d = d8 + j;
        unsigned by = (unsigned)(d * 128 + row * 2) ^ (unsigned)((((d & 7) ^ ((d >> 3) & 7))) << 4);
        *(unsigned short*)(Vt + by) = u.s[j];
      }
    }
    __syncthreads();                 // Vt ready
    // PV: A=P, B=Vt rows (contiguous 16B per lane)
    #pragma unroll
    for (int nf = 0; nf < 4; ++nf) {
      int d = nf * 16 + lm;
      unsigned swz = (unsigned)(((d & 7) ^ ((d >> 3) & 7)) << 4);
      bf16x8 v0 = *(const bf16x8*)(Vt + ((unsigned)(d * 128 + kg * 16) ^ swz));
      bf16x8 v1 = *(const bf16x8*)(Vt + ((unsigned)(d * 128 + 64 + kg * 16) ^ swz));
      o[nf] = __builtin_amdgcn_mfma_f32_16x16x32_bf16(pa0, v0, o[nf], 0, 0, 0);
      o[nf] = __builtin_amdgcn_mfma_f32_16x16x32_bf16(pa1, v1, o[nf], 0, 0, 0);
    }
  }
  // epilogue: normalize + store fp32
  float rl[4];
  #pragma unroll
  for (int i = 0; i < 4; ++i) rl[i] = 1.0f / lrow[i];
  #pragma unroll
  for (int nf = 0; nf < 4; ++nf) {
    #pragma unroll
    for (int i = 0; i < 4; ++i)
      out[(qrow0 + kg * 4 + i) * HD + nf * 16 + lm] = o[nf][i] * rl[i];
  }
}

extern "C" void kernel_launch(void* const* d_in, const int* in_sizes, int n_in,
                              void* d_out, int out_size, void* d_ws, size_t ws_size,
                              hipStream_t stream) {
  const float* q  = (const float*)d_in[0];
  const float* k  = (const float*)d_in[1];
  const float* v  = (const float*)d_in[2];
  const int* mask = (const int*)d_in[3];
  const float* Wq = (const float*)d_in[4];
  const float* bq = (const float*)d_in[5];
  const float* Wk = (const float*)d_in[6];
  const float* bk = (const float*)d_in[7];
  const float* Wv = (const float*)d_in[8];
  const float* bv = (const float*)d_in[9];
  uint8_t* ws = (uint8_t*)d_ws;
  float* out  = (float*)d_out;
  if (ws_size < WS_NEED) return;   // need ~6.7 MB scratch

  hipLaunchKernelGGL(cvt_kernel, dim3(576), dim3(256), 0, stream,
                     Wq, bq, Wk, bk, Wv, bv, ws);
  hipLaunchKernelGGL(proj_kernel, dim3(256, 3), dim3(256), 0, stream,
                     q, k, v, ws);
  hipLaunchKernelGGL(attn_kernel, dim3(SEQ / 32, NB), dim3(128), 0, stream,
                     ws, mask, out);
}

// Round 3
// 150.053 us; speedup vs baseline: 1.0716x; 1.0716x over previous
//
#include <hip/hip_runtime.h>
#include <stdint.h>

#define HID 768
#define HD  64
#define NB  8
#define SEQ 2048

typedef __bf16 bf16_t;
typedef __bf16 bf16x8 __attribute__((ext_vector_type(8)));
typedef __bf16 bf16x4 __attribute__((ext_vector_type(4)));
typedef float  f32x4  __attribute__((ext_vector_type(4)));
typedef int    i32x4  __attribute__((ext_vector_type(4)));

// workspace layout (bytes)
#define WT_OFF 0                         // bf16 WT[3][64][768]
#define B_OFF  (3*HD*HID*2)              // f32  bias[3][64]
#define Q_OFF  (512*1024)                // bf16 q[16384][64]   (row-major)
#define K_OFF  (Q_OFF + NB*SEQ*HD*2)     // bf16 k[16384][64]   (row-major)
#define V_OFF  (K_OFF + NB*SEQ*HD*2)     // bf16 vt[8][64][2048] (TRANSPOSED)
#define WS_NEED ((size_t)(V_OFF + NB*SEQ*HD*2))

#define ALPHA 0.18033688011112043f       // log2(e) / sqrt(64)

// ---------------- kernel 1: convert + transpose weights, fold scale ----------
__global__ __launch_bounds__(256) void cvt_kernel(
    const float* __restrict__ Wq, const float* __restrict__ bq,
    const float* __restrict__ Wk, const float* __restrict__ bk,
    const float* __restrict__ Wv, const float* __restrict__ bv,
    uint8_t* __restrict__ ws) {
  bf16_t* wt = (bf16_t*)(ws + WT_OFF);
  float*  bs = (float*)(ws + B_OFF);
  int idx = blockIdx.x * 256 + threadIdx.x;
  if (idx < 3 * HID * HD) {
    int n = idx & 63;
    int h = (idx >> 6) % HID;
    int t = idx / (HID * HD);
    const float* W = (t == 0) ? Wq : (t == 1) ? Wk : Wv;
    float v = W[h * HD + n];
    if (t == 0) v *= ALPHA;                    // prescale q path
    wt[(size_t)(t * HD + n) * HID + h] = (bf16_t)v;   // WT[t][n][h]
  }
  if (idx < 3 * HD) {
    int t = idx / HD, n = idx % HD;
    const float* bsrc = (t == 0) ? bq : (t == 1) ? bk : bv;
    bs[idx] = bsrc[n] * ((t == 0) ? ALPHA : 1.0f);
  }
}

// ---------------- kernel 2: projections  (V written TRANSPOSED) --------------
__global__ __launch_bounds__(256) void proj_kernel(
    const float* __restrict__ qin, const float* __restrict__ kin,
    const float* __restrict__ vin, uint8_t* __restrict__ ws) {
  const int t = blockIdx.y;
  const float* X = (t == 0) ? qin : (t == 1) ? kin : vin;
  const bf16_t* wt = (const bf16_t*)(ws + WT_OFF) + (size_t)t * HD * HID;
  const float* bias = (const float*)(ws + B_OFF) + t * HD;

  const int tid  = threadIdx.x;
  const int wid  = tid >> 6;
  const int lane = tid & 63;
  const int lm   = lane & 15;
  const int kg   = lane >> 4;
  const int r0   = blockIdx.x * 64 + wid * 16;

  f32x4 acc[4] = {{0,0,0,0},{0,0,0,0},{0,0,0,0},{0,0,0,0}};
  const float*  xp = X  + (size_t)(r0 + lm) * HID + kg * 8;
  const bf16_t* wp = wt + (size_t)lm * HID + kg * 8;

  #pragma unroll 2
  for (int kk = 0; kk < 24; ++kk) {
    f32x4 x0 = *(const f32x4*)(xp + kk * 32);
    f32x4 x1 = *(const f32x4*)(xp + kk * 32 + 4);
    bf16x8 xb;
    xb[0] = (bf16_t)x0[0]; xb[1] = (bf16_t)x0[1];
    xb[2] = (bf16_t)x0[2]; xb[3] = (bf16_t)x0[3];
    xb[4] = (bf16_t)x1[0]; xb[5] = (bf16_t)x1[1];
    xb[6] = (bf16_t)x1[2]; xb[7] = (bf16_t)x1[3];
    #pragma unroll
    for (int c = 0; c < 4; ++c) {
      bf16x8 wf = *(const bf16x8*)(wp + (size_t)c * 16 * HID + kk * 32);
      acc[c] = __builtin_amdgcn_mfma_f32_16x16x32_bf16(wf, xb, acc[c], 0, 0, 0);
    }
  }
  // D: col(lane&15)=x_row, row((lane>>4)*4+reg)=out_col
  if (t < 2) {
    bf16_t* out = (bf16_t*)(ws + Q_OFF) + (size_t)t * NB * SEQ * HD;
    #pragma unroll
    for (int c = 0; c < 4; ++c) {
      f32x4 b4 = *(const f32x4*)(bias + c * 16 + kg * 4);
      bf16x4 pk;
      pk[0] = (bf16_t)(acc[c][0] + b4[0]);
      pk[1] = (bf16_t)(acc[c][1] + b4[1]);
      pk[2] = (bf16_t)(acc[c][2] + b4[2]);
      pk[3] = (bf16_t)(acc[c][3] + b4[3]);
      *(bf16x4*)(out + (size_t)(r0 + lm) * HD + c * 16 + kg * 4) = pk;
    }
  } else {
    // V transposed: vt[b][d][s], d = c*16+kg*4+j, s = row & 2047
    bf16_t* vt = (bf16_t*)(ws + V_OFF);
    const int r  = r0 + lm;
    const int bi = r >> 11;
    const int s  = r & 2047;
    #pragma unroll
    for (int c = 0; c < 4; ++c) {
      f32x4 b4 = *(const f32x4*)(bias + c * 16 + kg * 4);
      #pragma unroll
      for (int j = 0; j < 4; ++j) {
        int d = c * 16 + kg * 4 + j;
        vt[((size_t)(bi * HD + d)) * SEQ + s] = (bf16_t)(acc[c][j] + b4[j]);
      }
    }
  }
}

// ---------------- kernel 3: flash attention (4-wave KV-split) ----------------
// Block = 256 threads (4 waves) owns ONE 16-row Q tile; wave w covers
// kv in [w*512, (w+1)*512). No LDS / no barriers in the main loop.
// Swapped QK^T: P[kv][q] lane-local per q-row. PV computes O^T = V^T * P with
// the P B-frag packed in-register and V^T A-frag loaded with the matching
// kv permutation (sigma(kg,j) = 4kg + (j&3) + 16*(j>>2) per 32-kv half).
__global__ __launch_bounds__(256, 4) void attn_kernel(
    const uint8_t* __restrict__ ws, const int* __restrict__ mask,
    float* __restrict__ out) {
  __shared__ __align__(16) float lds_o[4][64][17];   // [wave][d][q] padded
  __shared__ float lds_m[4][16];
  __shared__ float lds_l[4][16];

  const int blk  = blockIdx.x;
  const int b    = blk & 7;          // batch -> XCD (L2 locality)
  const int qt   = blk >> 3;         // q tile 0..127
  const int tid  = threadIdx.x;
  const int w    = tid >> 6;
  const int lane = tid & 63;
  const int lm   = lane & 15;
  const int kg   = lane >> 4;

  const bf16_t* qb = (const bf16_t*)(ws + Q_OFF);
  const bf16_t* kbase = (const bf16_t*)(ws + K_OFF) + (size_t)b * SEQ * HD;
  const bf16_t* vt = (const bf16_t*)(ws + V_OFF) + (size_t)b * HD * SEQ;
  const int* mp = mask + b * SEQ;

  const int qrow0 = b * SEQ + qt * 16;
  // Q B-frag: B-col = lm = q row, k-slot (kg,j) <- d = kg*8+j
  bf16x8 qf0 = *(const bf16x8*)(qb + (size_t)(qrow0 + lm) * HD + kg * 8);
  bf16x8 qf1 = *(const bf16x8*)(qb + (size_t)(qrow0 + lm) * HD + 32 + kg * 8);

  f32x4 o[4] = {{0,0,0,0},{0,0,0,0},{0,0,0,0},{0,0,0,0}};
  float m_run = -1e30f;   // per-lane, q = lm
  float l_run = 0.f;

  const int kv_lo = w * (SEQ / 4);
  // V^T row pointer for this lane's d-rows: d = nf2*16 + lm
  const bf16_t* vrow[4];
  #pragma unroll
  for (int nf2 = 0; nf2 < 4; ++nf2)
    vrow[nf2] = vt + (size_t)(nf2 * 16 + lm) * SEQ;

  for (int it = 0; it < (SEQ / 4) / 64; ++it) {
    const int kv0 = kv_lo + it * 64;

    // ---- QK^T: A = K rows (A-row = kv = nf*16+lm), B = Q ----
    f32x4 sc[4];
    #pragma unroll
    for (int nf = 0; nf < 4; ++nf) {
      const bf16_t* kp = kbase + (size_t)(kv0 + nf * 16 + lm) * HD + kg * 8;
      bf16x8 k0 = *(const bf16x8*)(kp);
      bf16x8 k1 = *(const bf16x8*)(kp + 32);
      f32x4 z = {0.f, 0.f, 0.f, 0.f};
      z = __builtin_amdgcn_mfma_f32_16x16x32_bf16(k0, qf0, z, 0, 0, 0);
      z = __builtin_amdgcn_mfma_f32_16x16x32_bf16(k1, qf1, z, 0, 0, 0);
      sc[nf] = z;   // P[kv = nf*16 + kg*4 + i][q = lm]
    }

    // ---- V^T A-frags (issue early; L2-resident) ----
    // frag (nf2, h): element j <- vt[d = nf2*16+lm][kv0 + 32h + 4kg + (j&3) + 16*(j>>2)]
    bf16x8 va[4][2];
    #pragma unroll
    for (int nf2 = 0; nf2 < 4; ++nf2) {
      const bf16_t* vr = vrow[nf2] + kv0 + 4 * kg;
      #pragma unroll
      for (int h = 0; h < 2; ++h) {
        union { bf16x8 v8; bf16x4 v4[2]; } u;
        u.v4[0] = *(const bf16x4*)(vr + 32 * h);
        u.v4[1] = *(const bf16x4*)(vr + 32 * h + 16);
        va[nf2][h] = u.v8;
      }
    }

    // ---- mask (kv = kv0 + nf*16 + kg*4 + i) ----
    #pragma unroll
    for (int nf = 0; nf < 4; ++nf) {
      i32x4 mv = *(const i32x4*)(mp + kv0 + nf * 16 + kg * 4);
      #pragma unroll
      for (int i = 0; i < 4; ++i)
        if (mv[i] == 0) sc[nf][i] = -1e30f;
    }

    // ---- online softmax (per-lane scalars, q = lm) ----
    float pm = sc[0][0];
    #pragma unroll
    for (int nf = 0; nf < 4; ++nf)
      #pragma unroll
      for (int i = 0; i < 4; ++i) pm = fmaxf(pm, sc[nf][i]);
    pm = fmaxf(pm, __shfl_xor(pm, 16));
    pm = fmaxf(pm, __shfl_xor(pm, 32));
    float mn = fmaxf(m_run, pm);
    float corr = __builtin_amdgcn_exp2f(m_run - mn);
    m_run = mn;
    float s_loc = 0.f;
    #pragma unroll
    for (int nf = 0; nf < 4; ++nf)
      #pragma unroll
      for (int i = 0; i < 4; ++i) {
        float p = __builtin_amdgcn_exp2f(sc[nf][i] - mn);
        sc[nf][i] = p;
        s_loc += p;
      }
    s_loc += __shfl_xor(s_loc, 16);
    s_loc += __shfl_xor(s_loc, 32);
    l_run = l_run * corr + s_loc;
    #pragma unroll
    for (int nf2 = 0; nf2 < 4; ++nf2) {
      o[nf2][0] *= corr; o[nf2][1] *= corr; o[nf2][2] *= corr; o[nf2][3] *= corr;
    }

    // ---- pack P B-frags: half h covers kv 32h..32h+31 ----
    bf16x8 pb[2];
    #pragma unroll
    for (int h = 0; h < 2; ++h) {
      bf16x8 p8;
      p8[0] = (bf16_t)sc[2 * h][0];     p8[1] = (bf16_t)sc[2 * h][1];
      p8[2] = (bf16_t)sc[2 * h][2];     p8[3] = (bf16_t)sc[2 * h][3];
      p8[4] = (bf16_t)sc[2 * h + 1][0]; p8[5] = (bf16_t)sc[2 * h + 1][1];
      p8[6] = (bf16_t)sc[2 * h + 1][2]; p8[7] = (bf16_t)sc[2 * h + 1][3];
      pb[h] = p8;
    }

    // ---- PV: O^T[d][q] accumulate ----
    #pragma unroll
    for (int nf2 = 0; nf2 < 4; ++nf2) {
      o[nf2] = __builtin_amdgcn_mfma_f32_16x16x32_bf16(va[nf2][0], pb[0], o[nf2], 0, 0, 0);
      o[nf2] = __builtin_amdgcn_mfma_f32_16x16x32_bf16(va[nf2][1], pb[1], o[nf2], 0, 0, 0);
    }
  }

  // ---- write partials to LDS ----
  #pragma unroll
  for (int nf2 = 0; nf2 < 4; ++nf2)
    #pragma unroll
    for (int i = 0; i < 4; ++i)
      lds_o[w][nf2 * 16 + kg * 4 + i][lm] = o[nf2][i];
  if (lane < 16) {
    lds_m[w][lane] = m_run;
    lds_l[w][lane] = l_run;
  }
  __syncthreads();

  // ---- combine 4 waves, store fp32 out ----
  {
    const int q  = tid >> 4;          // 0..15
    const int d0 = (tid & 15) * 4;    // 0..60
    float mw[4], m_tot;
    #pragma unroll
    for (int ww = 0; ww < 4; ++ww) mw[ww] = lds_m[ww][q];
    m_tot = fmaxf(fmaxf(mw[0], mw[1]), fmaxf(mw[2], mw[3]));
    float den = 0.f;
    f32x4 num = {0.f, 0.f, 0.f, 0.f};
    #pragma unroll
    for (int ww = 0; ww < 4; ++ww) {
      float f = __builtin_amdgcn_exp2f(mw[ww] - m_tot);
      den += lds_l[ww][q] * f;
      #pragma unroll
      for (int j = 0; j < 4; ++j)
        num[j] += lds_o[ww][d0 + j][q] * f;
    }
    float r = 1.0f / den;
    f32x4 res = {num[0] * r, num[1] * r, num[2] * r, num[3] * r};
    *(f32x4*)(out + (size_t)(qrow0 + q) * HD + d0) = res;
  }
}

extern "C" void kernel_launch(void* const* d_in, const int* in_sizes, int n_in,
                              void* d_out, int out_size, void* d_ws, size_t ws_size,
                              hipStream_t stream) {
  const float* q  = (const float*)d_in[0];
  const float* k  = (const float*)d_in[1];
  const float* v  = (const float*)d_in[2];
  const int* mask = (const int*)d_in[3];
  const float* Wq = (const float*)d_in[4];
  const float* bq = (const float*)d_in[5];
  const float* Wk = (const float*)d_in[6];
  const float* bk = (const float*)d_in[7];
  const float* Wv = (const float*)d_in[8];
  const float* bv = (const float*)d_in[9];
  uint8_t* ws = (uint8_t*)d_ws;
  float* out  = (float*)d_out;
  if (ws_size < WS_NEED) return;   // need ~6.7 MB scratch

  hipLaunchKernelGGL(cvt_kernel, dim3(576), dim3(256), 0, stream,
                     Wq, bq, Wk, bk, Wv, bv, ws);
  hipLaunchKernelGGL(proj_kernel, dim3(256, 3), dim3(256), 0, stream,
                     q, k, v, ws);
  hipLaunchKernelGGL(attn_kernel, dim3(NB * SEQ / 16), dim3(256), 0, stream,
                     ws, mask, out);
}

// Round 4
// 86.692 us; speedup vs baseline: 1.8548x; 1.7309x over previous
//
#include <hip/hip_runtime.h>
#include <stdint.h>

#define HID 768
#define HD  64
#define NB  8
#define SEQ 2048

typedef __bf16 bf16_t;
typedef __bf16 bf16x8 __attribute__((ext_vector_type(8)));
typedef __bf16 bf16x4 __attribute__((ext_vector_type(4)));
typedef float  f32x4  __attribute__((ext_vector_type(4)));
typedef int    i32x4  __attribute__((ext_vector_type(4)));

typedef const __attribute__((address_space(1))) uint32_t* gptr_t;
typedef __attribute__((address_space(3))) uint32_t* lptr_t;

// workspace layout (bytes)
#define WT_OFF 0                         // bf16 WT[3][64][768]
#define B_OFF  (3*HD*HID*2)              // f32  bias[3][64]
#define Q_OFF  (512*1024)                // bf16 q[16384][64]   (row-major)
#define K_OFF  (Q_OFF + NB*SEQ*HD*2)     // bf16 k[16384][64]   (row-major)
#define V_OFF  (K_OFF + NB*SEQ*HD*2)     // bf16 vt[8][64][2048] (TRANSPOSED)
#define WS_NEED ((size_t)(V_OFF + NB*SEQ*HD*2))

#define ALPHA 0.18033688011112043f       // log2(e) / sqrt(64)

// ---------------- kernel 1: convert + transpose weights, fold scale ----------
__global__ __launch_bounds__(256) void cvt_kernel(
    const float* __restrict__ Wq, const float* __restrict__ bq,
    const float* __restrict__ Wk, const float* __restrict__ bk,
    const float* __restrict__ Wv, const float* __restrict__ bv,
    uint8_t* __restrict__ ws) {
  bf16_t* wt = (bf16_t*)(ws + WT_OFF);
  float*  bs = (float*)(ws + B_OFF);
  int idx = blockIdx.x * 256 + threadIdx.x;
  if (idx < 3 * HID * HD) {
    int n = idx & 63;
    int h = (idx >> 6) % HID;
    int t = idx / (HID * HD);
    const float* W = (t == 0) ? Wq : (t == 1) ? Wk : Wv;
    float v = W[h * HD + n];
    if (t == 0) v *= ALPHA;                    // prescale q path
    wt[(size_t)(t * HD + n) * HID + h] = (bf16_t)v;   // WT[t][n][h]
  }
  if (idx < 3 * HD) {
    int t = idx / HD, n = idx % HD;
    const float* bsrc = (t == 0) ? bq : (t == 1) ? bk : bv;
    bs[idx] = bsrc[n] * ((t == 0) ? ALPHA : 1.0f);
  }
}

// ---------------- kernel 2: projections  (V written TRANSPOSED) --------------
__global__ __launch_bounds__(256) void proj_kernel(
    const float* __restrict__ qin, const float* __restrict__ kin,
    const float* __restrict__ vin, uint8_t* __restrict__ ws) {
  const int t = blockIdx.y;
  const float* X = (t == 0) ? qin : (t == 1) ? kin : vin;
  const bf16_t* wt = (const bf16_t*)(ws + WT_OFF) + (size_t)t * HD * HID;
  const float* bias = (const float*)(ws + B_OFF) + t * HD;

  const int tid  = threadIdx.x;
  const int wid  = tid >> 6;
  const int lane = tid & 63;
  const int lm   = lane & 15;
  const int kg   = lane >> 4;
  const int r0   = blockIdx.x * 64 + wid * 16;

  f32x4 acc[4] = {{0,0,0,0},{0,0,0,0},{0,0,0,0},{0,0,0,0}};
  const float*  xp = X  + (size_t)(r0 + lm) * HID + kg * 8;
  const bf16_t* wp = wt + (size_t)lm * HID + kg * 8;

  #pragma unroll 2
  for (int kk = 0; kk < 24; ++kk) {
    f32x4 x0 = *(const f32x4*)(xp + kk * 32);
    f32x4 x1 = *(const f32x4*)(xp + kk * 32 + 4);
    bf16x8 xb;
    xb[0] = (bf16_t)x0[0]; xb[1] = (bf16_t)x0[1];
    xb[2] = (bf16_t)x0[2]; xb[3] = (bf16_t)x0[3];
    xb[4] = (bf16_t)x1[0]; xb[5] = (bf16_t)x1[1];
    xb[6] = (bf16_t)x1[2]; xb[7] = (bf16_t)x1[3];
    #pragma unroll
    for (int c = 0; c < 4; ++c) {
      bf16x8 wf = *(const bf16x8*)(wp + (size_t)c * 16 * HID + kk * 32);
      acc[c] = __builtin_amdgcn_mfma_f32_16x16x32_bf16(wf, xb, acc[c], 0, 0, 0);
    }
  }
  // D: col(lane&15)=x_row, row((lane>>4)*4+reg)=out_col
  if (t < 2) {
    bf16_t* out = (bf16_t*)(ws + Q_OFF) + (size_t)t * NB * SEQ * HD;
    #pragma unroll
    for (int c = 0; c < 4; ++c) {
      f32x4 b4 = *(const f32x4*)(bias + c * 16 + kg * 4);
      bf16x4 pk;
      pk[0] = (bf16_t)(acc[c][0] + b4[0]);
      pk[1] = (bf16_t)(acc[c][1] + b4[1]);
      pk[2] = (bf16_t)(acc[c][2] + b4[2]);
      pk[3] = (bf16_t)(acc[c][3] + b4[3]);
      *(bf16x4*)(out + (size_t)(r0 + lm) * HD + c * 16 + kg * 4) = pk;
    }
  } else {
    // V transposed: vt[b][d][s]
    bf16_t* vt = (bf16_t*)(ws + V_OFF);
    const int r  = r0 + lm;
    const int bi = r >> 11;
    const int s  = r & 2047;
    #pragma unroll
    for (int c = 0; c < 4; ++c) {
      f32x4 b4 = *(const f32x4*)(bias + c * 16 + kg * 4);
      #pragma unroll
      for (int j = 0; j < 4; ++j) {
        int d = c * 16 + kg * 4 + j;
        vt[((size_t)(bi * HD + d)) * SEQ + s] = (bf16_t)(acc[c][j] + b4[j]);
      }
    }
  }
}

// ---------------- kernel 3: flash attention (LDS-staged, 2-phase) ------------
// 512 blocks x 256 thr (4 waves). Block owns 32 q-rows of batch b = blk&7.
// 2 kv-groups x 2 waves; group g covers kv [g*1024, g*1024+1024).
// Per group: double-buffered LDS tile (K 8KB + Vt 8KB), staged with
// global_load_lds width-16, row-XOR swizzle applied on the SOURCE address
// (LDS dest linear) and the same XOR on ds_read side.
__device__ __forceinline__ void stage_tiles(
    const bf16_t* kbase, const bf16_t* vtb, uint8_t* buf,
    int kvo, int s4, int lane) {
  #pragma unroll
  for (int i = 0; i < 4; ++i) {
    int qi = s4 * 4 + i;               // 0..7 across the 2 waves of the group
    int r  = qi * 8 + (lane >> 3);     // row (K: kv row; V: d row)
    int c  = lane & 7;                 // 16B chunk within 128B row
    const bf16_t* gk = kbase + (size_t)(kvo + r) * HD + ((c ^ (r & 7)) * 8);
    __builtin_amdgcn_global_load_lds((gptr_t)gk, (lptr_t)(buf + qi * 1024), 16, 0, 0);
    const bf16_t* gv = vtb + (size_t)r * SEQ + kvo + ((c ^ (r & 7)) * 8);
    __builtin_amdgcn_global_load_lds((gptr_t)gv, (lptr_t)(buf + 8192 + qi * 1024), 16, 0, 0);
  }
}

__global__ __launch_bounds__(256, 2) void attn_kernel(
    const uint8_t* __restrict__ ws, const int* __restrict__ mask,
    float* __restrict__ out) {
  __shared__ __align__(16) uint8_t smem[4 * 16384 + 512];
  const int blk  = blockIdx.x;
  const int b    = blk & 7;          // batch -> XCD (L2 locality)
  const int qt   = blk >> 3;         // q tile 0..63
  const int tid  = threadIdx.x;
  const int w    = tid >> 6;
  const int g4   = w >> 1;           // kv group
  const int s4   = w & 1;            // sub-wave in group
  const int lane = tid & 63;
  const int lm   = lane & 15;
  const int kg   = lane >> 4;

  const bf16_t* qb = (const bf16_t*)(ws + Q_OFF);
  const bf16_t* kbase = (const bf16_t*)(ws + K_OFF) + (size_t)b * SEQ * HD;
  const bf16_t* vtb = (const bf16_t*)(ws + V_OFF) + (size_t)b * HD * SEQ;
  const int* mp = mask + b * SEQ;

  const int qrow0 = b * SEQ + qt * 32;          // block's first q row
  const int qrw   = qrow0 + s4 * 16;            // this wave's 16 q rows
  bf16x8 qf0 = *(const bf16x8*)(qb + (size_t)(qrw + lm) * HD + kg * 8);
  bf16x8 qf1 = *(const bf16x8*)(qb + (size_t)(qrw + lm) * HD + 32 + kg * 8);

  f32x4 o[4] = {{0,0,0,0},{0,0,0,0},{0,0,0,0},{0,0,0,0}};
  float m_run = -1e30f;   // per-lane, q = lm (same across kg after reduce)
  float l_run = 0.f;

  uint8_t* mytiles = smem + g4 * 32768;         // 2 bufs x 16KB
  const int kv_lo = g4 * 1024;

  stage_tiles(kbase, vtb, mytiles, kv_lo, s4, lane);
  __syncthreads();                               // drains vmcnt -> buf0 ready

  #pragma unroll 1
  for (int it = 0; it < 16; ++it) {
    uint8_t* cur = mytiles + (it & 1) * 16384;
    uint8_t* nxt = mytiles + ((it & 1) ^ 1) * 16384;
    const int kvo = kv_lo + it * 64;
    if (it < 15) stage_tiles(kbase, vtb, nxt, kvo + 64, s4, lane);

    // mask loads (early, L2-hot)
    i32x4 mv[4];
    #pragma unroll
    for (int nf = 0; nf < 4; ++nf)
      mv[nf] = *(const i32x4*)(mp + kvo + nf * 16 + kg * 4);

    // ---- QK^T from LDS ----
    const uint8_t* Kb = cur;
    const uint8_t* Vb = cur + 8192;
    f32x4 sc[4];
    #pragma unroll
    for (int nf = 0; nf < 4; ++nf) {
      int r = nf * 16 + lm;
      bf16x8 k0 = *(const bf16x8*)(Kb + r * 128 + ((kg ^ (r & 7)) << 4));
      bf16x8 k1 = *(const bf16x8*)(Kb + r * 128 + (((4 + kg) ^ (r & 7)) << 4));
      f32x4 z = {0.f, 0.f, 0.f, 0.f};
      z = __builtin_amdgcn_mfma_f32_16x16x32_bf16(k0, qf0, z, 0, 0, 0);
      z = __builtin_amdgcn_mfma_f32_16x16x32_bf16(k1, qf1, z, 0, 0, 0);
      sc[nf] = z;   // P[kv = nf*16 + kg*4 + i][q = lm]
    }

    // ---- mask ----
    #pragma unroll
    for (int nf = 0; nf < 4; ++nf)
      #pragma unroll
      for (int i = 0; i < 4; ++i)
        if (mv[nf][i] == 0) sc[nf][i] = -1e30f;

    // ---- online softmax (per-lane scalars, q = lm) ----
    float pm = sc[0][0];
    #pragma unroll
    for (int nf = 0; nf < 4; ++nf)
      #pragma unroll
      for (int i = 0; i < 4; ++i) pm = fmaxf(pm, sc[nf][i]);
    pm = fmaxf(pm, __shfl_xor(pm, 16));
    pm = fmaxf(pm, __shfl_xor(pm, 32));
    float mn = fmaxf(m_run, pm);
    float corr = __builtin_amdgcn_exp2f(m_run - mn);
    m_run = mn;
    float s_loc = 0.f;
    #pragma unroll
    for (int nf = 0; nf < 4; ++nf)
      #pragma unroll
      for (int i = 0; i < 4; ++i) {
        float p = __builtin_amdgcn_exp2f(sc[nf][i] - mn);
        sc[nf][i] = p;
        s_loc += p;
      }
    s_loc += __shfl_xor(s_loc, 16);
    s_loc += __shfl_xor(s_loc, 32);
    l_run = l_run * corr + s_loc;
    #pragma unroll
    for (int nf2 = 0; nf2 < 4; ++nf2) {
      o[nf2][0] *= corr; o[nf2][1] *= corr; o[nf2][2] *= corr; o[nf2][3] *= corr;
    }

    // ---- pack P B-frags ----
    bf16x8 pb[2];
    #pragma unroll
    for (int h = 0; h < 2; ++h) {
      bf16x8 p8;
      p8[0] = (bf16_t)sc[2 * h][0];     p8[1] = (bf16_t)sc[2 * h][1];
      p8[2] = (bf16_t)sc[2 * h][2];     p8[3] = (bf16_t)sc[2 * h][3];
      p8[4] = (bf16_t)sc[2 * h + 1][0]; p8[5] = (bf16_t)sc[2 * h + 1][1];
      p8[6] = (bf16_t)sc[2 * h + 1][2]; p8[7] = (bf16_t)sc[2 * h + 1][3];
      pb[h] = p8;
    }

    // ---- PV: V^T A-frags from LDS (b64 granules, swizzled) ----
    #pragma unroll
    for (int nf2 = 0; nf2 < 4; ++nf2) {
      int d = nf2 * 16 + lm;
      #pragma unroll
      for (int h2 = 0; h2 < 2; ++h2) {
        int B1 = 8 * kg + 64 * h2;
        int B2 = B1 + 32;
        union { bf16x8 v8; bf16x4 v4[2]; } u;
        u.v4[0] = *(const bf16x4*)(Vb + d * 128 + (((B1 >> 4) ^ (d & 7)) << 4) + (B1 & 15));
        u.v4[1] = *(const bf16x4*)(Vb + d * 128 + (((B2 >> 4) ^ (d & 7)) << 4) + (B2 & 15));
        o[nf2] = __builtin_amdgcn_mfma_f32_16x16x32_bf16(u.v8, pb[h2], o[nf2], 0, 0, 0);
      }
    }
    __syncthreads();   // drains stage vmcnt; releases cur for restaging
  }

  // ---- partials to LDS (overlay on tile region) ----
  float* lds_o  = (float*)smem;                  // [4][64][17]
  float* lds_ml = (float*)(smem + 4 * 16384);    // [4][16][2]
  #pragma unroll
  for (int nf2 = 0; nf2 < 4; ++nf2)
    #pragma unroll
    for (int i = 0; i < 4; ++i)
      lds_o[(w * 64 + nf2 * 16 + kg * 4 + i) * 17 + lm] = o[nf2][i];
  if (lane < 16) {
    lds_ml[(w * 16 + lane) * 2 + 0] = m_run;
    lds_ml[(w * 16 + lane) * 2 + 1] = l_run;
  }
  __syncthreads();

  // ---- combine the 2 kv-groups, store fp32 ----
  {
    const int row = tid >> 3;        // 0..31
    const int d0  = (tid & 7) * 8;
    const int s   = row >> 4, lmq = row & 15;
    const int w1  = s, w2 = 2 + s;   // wave ids (g0,s) and (g1,s)
    float m1 = lds_ml[(w1 * 16 + lmq) * 2], l1 = lds_ml[(w1 * 16 + lmq) * 2 + 1];
    float m2 = lds_ml[(w2 * 16 + lmq) * 2], l2 = lds_ml[(w2 * 16 + lmq) * 2 + 1];
    float mt = fmaxf(m1, m2);
    float f1 = __builtin_amdgcn_exp2f(m1 - mt);
    float f2 = __builtin_amdgcn_exp2f(m2 - mt);
    float rden = 1.0f / (l1 * f1 + l2 * f2);
    float res[8];
    #pragma unroll
    for (int j = 0; j < 8; ++j) {
      float n1 = lds_o[(w1 * 64 + d0 + j) * 17 + lmq];
      float n2 = lds_o[(w2 * 64 + d0 + j) * 17 + lmq];
      res[j] = (n1 * f1 + n2 * f2) * rden;
    }
    float* op = out + (size_t)(qrow0 + row) * HD + d0;
    *(f32x4*)op = *(f32x4*)&res[0];
    *(f32x4*)(op + 4) = *(f32x4*)&res[4];
  }
}

extern "C" void kernel_launch(void* const* d_in, const int* in_sizes, int n_in,
                              void* d_out, int out_size, void* d_ws, size_t ws_size,
                              hipStream_t stream) {
  const float* q  = (const float*)d_in[0];
  const float* k  = (const float*)d_in[1];
  const float* v  = (const float*)d_in[2];
  const int* mask = (const int*)d_in[3];
  const float* Wq = (const float*)d_in[4];
  const float* bq = (const float*)d_in[5];
  const float* Wk = (const float*)d_in[6];
  const float* bk = (const float*)d_in[7];
  const float* Wv = (const float*)d_in[8];
  const float* bv = (const float*)d_in[9];
  uint8_t* ws = (uint8_t*)d_ws;
  float* out  = (float*)d_out;
  if (ws_size < WS_NEED) return;   // need ~6.7 MB scratch

  hipLaunchKernelGGL(cvt_kernel, dim3(576), dim3(256), 0, stream,
                     Wq, bq, Wk, bk, Wv, bv, ws);
  hipLaunchKernelGGL(proj_kernel, dim3(256, 3), dim3(256), 0, stream,
                     q, k, v, ws);
  hipLaunchKernelGGL(attn_kernel, dim3(NB * SEQ / 32), dim3(256), 0, stream,
                     ws, mask, out);
}